// Round 2
// baseline (380.665 us; speedup 1.0000x reference)
//
#include <hip/hip_runtime.h>

namespace {

constexpr int BATCH = 16;
constexpr int HH = 512;
constexpr int WW = 512;
constexpr int PLANE = HH * WW;
constexpr int NPAIR = BATCH * (HH / 8) * (WW / 16);  // 32768 block-pairs
constexpr int NWG = 3072;                            // 12 blocks/CU, all co-resident

// ---- numpy-faithful cosine table (DO NOT TOUCH — decision-path numerics) ----
constexpr double PI64 = 3.141592653589793;
constexpr double PI_LO = 1.2246467991473532e-16;
constexpr double PI_HI = (double)((long long)(PI64 * 17592186044416.0)) / 17592186044416.0;
constexpr double PI_MID = PI64 - PI_HI;

constexpr double CD9[9] = {
    1.0,
    0.9807852804032304491,
    0.9238795325112867561,
    0.8314696123025452371,
    0.7071067811865475244,
    0.5555702330196022248,
    0.3826834323650897717,
    0.1950903220161282678,
    0.0};
constexpr double cos_tab(int m) {
    m %= 32;
    double s = 1.0;
    if (m > 16) m = 32 - m;
    if (m > 8) { s = -1.0; m = 16 - m; }
    return s * CD9[m];
}
constexpr double sin_tab(int m) { return cos_tab(m + 24); }

constexpr double cx64(int K) {
    float Kf = (float)K;
    float p32 = (float)PI64;
    float t32 = Kf * p32;
    double F = (double)t32;
    double E = ((F - (double)K * PI_HI) - (double)K * PI_MID) - (double)K * PI_LO;
    double r = E / 16.0;
    double C = cos_tab(K), S = sin_tab(K);
    double cr = 1.0 - 0.5 * r * r;
    double sr = r - (r * r * r) / 6.0;
    return C * cr - S * sr;
}
constexpr float cx32(int x, int u) { return (float)cx64((2 * x + 1) * u); }

struct C32A { float c[64]; };
constexpr C32A make_c32f() {
    C32A a{};
    for (int x = 0; x < 8; ++x)
        for (int u = 0; u < 8; ++u)
            a.c[x * 8 + u] = cx32(x, u);
    return a;
}
constexpr C32A C32F = make_c32f();

constexpr float YQ[64] = {
    16, 11, 10, 16, 24, 40, 51, 61,
    12, 12, 14, 19, 26, 58, 60, 55,
    14, 13, 16, 24, 40, 57, 69, 56,
    14, 17, 22, 29, 51, 87, 80, 62,
    18, 22, 37, 56, 68, 109, 103, 77,
    24, 35, 55, 64, 81, 104, 113, 92,
    49, 64, 78, 87, 103, 121, 120, 101,
    72, 92, 95, 98, 112, 100, 103, 99};

constexpr float CQ[64] = {
    17, 18, 24, 47, 99, 99, 99, 99,
    18, 21, 26, 66, 99, 99, 99, 99,
    24, 26, 56, 99, 99, 99, 99, 99,
    47, 66, 99, 99, 99, 99, 99, 99,
    99, 99, 99, 99, 99, 99, 99, 99,
    99, 99, 99, 99, 99, 99, 99, 99,
    99, 99, 99, 99, 99, 99, 99, 99,
    99, 99, 99, 99, 99, 99, 99, 99};

constexpr float AL32 = (float)0.7071067811865475244;

struct QuantD { double m[64]; double qty[64]; double qtc[64]; double dqy[64]; double dqc[64]; };
constexpr QuantD make_qd() {
    QuantD q{};
    for (int u = 0; u < 8; ++u)
        for (int v = 0; v < 8; ++v) {
            int i = u * 8 + v;
            float aa = (u == 0 ? AL32 : 1.0f) * (v == 0 ? AL32 : 1.0f);
            q.m[i]   = (double)(aa * 0.25f);
            q.qty[i] = (double)YQ[i];
            q.qtc[i] = (double)CQ[i];
            q.dqy[i] = (double)YQ[i] * (double)aa;
            q.dqc[i] = (double)CQ[i] * (double)aa;
        }
    return q;
}
constexpr QuantD QD = make_qd();

} // namespace

// fp64 color transform — bit-identical (decision path).
__device__ __forceinline__ void color_f64(float Rf, float Gf, float Bf,
                                          double& yv, double& cbv, double& crv) {
    const double rv = ((double)Rf + 1.0) * 127.5;
    const double gv = ((double)Gf + 1.0) * 127.5;
    const double bv = ((double)Bf + 1.0) * 127.5;
    yv = ((double)0.299f * rv + (double)0.587f * gv) + (double)0.114f * bv;
    yv = yv - 128.0;
    cbv = ((double)-0.168736f * rv + (double)-0.331264f * gv) + (double)0.5f * bv;
    cbv = (cbv + 128.0) - 128.0;
    crv = ((double)0.5f * rv + (double)-0.418688f * gv) + (double)-0.081312f * bv;
    crv = (crv + 128.0) - 128.0;
}

__device__ __forceinline__ float clamp255(float x) {
    return fminf(fmaxf(x, 0.0f), 255.0f) * (1.0f / 255.0f);
}

// One wave = one PAIR of horizontally adjacent 8x8 blocks per iteration.
__global__ __launch_bounds__(64, 3) void jpeg_kernel(const float* __restrict__ in,
                                                     float* __restrict__ out) {
    __shared__ __align__(16) double sYd[2][3][64];  // pair x channel x spatial (f64)
    __shared__ __align__(16) float  sF [2][3][64];  // dequantized*alpha coefficients [u][v]
    __shared__ __align__(16) float  sGt[2][3][96];  // idct stage-1, TRANSPOSED [y][u], stride 12

    const int lane = threadIdx.x;     // 0..63
    const int px = lane >> 3;         // row within block / u-index for DCT
    const int py = lane & 7;          // col index        / v-index for DCT

    // ---- one-time per-lane constants (all VGPR-resident, no 128-reg f64 table) ----
    // T[uv][x*8+y] = (double)( fl32( c[x][u] * c[y][v] ) )  — rank-1 remat,
    // bit-identical to the constexpr DCTT table of prior rounds.
    float Tf[64];
    {
        float cu[8], cv[8];
        #pragma unroll
        for (int k = 0; k < 8; ++k) {
            cu[k] = C32F.c[k * 8 + px];   // c[x][u], u = lane>>3
            cv[k] = C32F.c[k * 8 + py];   // c[y][v], v = lane&7
        }
        #pragma unroll
        for (int x = 0; x < 8; ++x)
            #pragma unroll
            for (int y = 0; y < 8; ++y)
                Tf[x * 8 + y] = cu[x] * cv[y];  // exact f32 mul == constexpr table
    }
    // idct cosine rows, hoisted out of the loop (formerly LDS reads each phase)
    float cyv[8], cxu[8];
    #pragma unroll
    for (int k = 0; k < 8; ++k) {
        cyv[k] = C32F.c[py * 8 + k];      // stage-1 row (yy = lane&7)
        cxu[k] = C32F.c[px * 8 + k];      // stage-2 row (px = lane>>3)
    }

    const double m   = QD.m[lane];
    const double qty = QD.qty[lane], qtc = QD.qtc[lane];
    const double dqy = QD.dqy[lane], dqc = QD.dqc[lane];

    const int blkL = py >> 2;         // which block this lane's pixel-pair is in
    const int col0 = (py & 3) * 2;    // first of two adjacent columns in that block

    #pragma unroll 1
    for (int P = blockIdx.x; P < NPAIR; P += NWG) {
        const int b = P >> 11;              // image (2048 pairs per image)
        const int p2 = P & 2047;
        const int by = p2 >> 5;             // block row (64 rows)
        const int pbx = p2 & 31;            // pair col (32 pairs per row)
        const size_t rowbase = (size_t)b * 3 * PLANE + (size_t)(by * 8 + px) * WW
                             + (size_t)(pbx * 16);

        // ---- full-cache-line loads: float2 per lane per channel ----
        const float2 Rp = *(const float2*)(in + rowbase + 2 * py);
        const float2 Gp = *(const float2*)(in + rowbase + PLANE + 2 * py);
        const float2 Bp = *(const float2*)(in + rowbase + 2 * (size_t)PLANE + 2 * py);

        __syncthreads();   // prior iteration's DCT dots are done with sYd

        {
            double y0, cb0, cr0, y1, cb1, cr1;
            color_f64(Rp.x, Gp.x, Bp.x, y0, cb0, cr0);
            color_f64(Rp.y, Gp.y, Bp.y, y1, cb1, cr1);
            const int si = px * 8 + col0;
            *(double2*)&sYd[blkL][0][si] = make_double2(y0, y1);
            *(double2*)&sYd[blkL][1][si] = make_double2(cb0, cb1);
            *(double2*)&sYd[blkL][2][si] = make_double2(cr0, cr1);
        }
        __syncthreads();

        // ---- 6 independent fp64 DCT dots + diff-round quant.
        //      Chain structure & FMA order bit-identical to prior rounds;
        //      Y broadcast reads vectorized to double2 (192 b128/pair). ----
        float Fv[2][3];
        #pragma unroll
        for (int blk = 0; blk < 2; ++blk) {
            #pragma unroll
            for (int ch = 0; ch < 3; ++ch) {
                const double2* __restrict__ Y2 = (const double2*)&sYd[blk][ch][0];
                double a0 = 0.0, a1 = 0.0, a2 = 0.0, a3 = 0.0;
                #pragma unroll
                for (int j = 0; j < 8; ++j) {
                    const double2 w0 = Y2[j];
                    const double2 w1 = Y2[j + 8];
                    const double2 w2 = Y2[j + 16];
                    const double2 w3 = Y2[j + 24];
                    a0 = __builtin_fma((double)Tf[2 * j],      w0.x, a0);
                    a0 = __builtin_fma((double)Tf[2 * j + 1],  w0.y, a0);
                    a1 = __builtin_fma((double)Tf[2 * j + 16], w1.x, a1);
                    a1 = __builtin_fma((double)Tf[2 * j + 17], w1.y, a1);
                    a2 = __builtin_fma((double)Tf[2 * j + 32], w2.x, a2);
                    a2 = __builtin_fma((double)Tf[2 * j + 33], w2.y, a2);
                    a3 = __builtin_fma((double)Tf[2 * j + 48], w3.x, a3);
                    a3 = __builtin_fma((double)Tf[2 * j + 49], w3.y, a3);
                }
                const double S = (a0 + a1) + (a2 + a3);
                const double qtd = (ch == 0) ? qty : qtc;
                const double dq  = (ch == 0) ? dqy : dqc;
                const double f = (m * S) / qtd;        // true f64 divide
                const double rr = __builtin_rint(f);   // half-to-even
                const double d = f - rr;
                Fv[blk][ch] = (float)((rr + (d * d) * d) * dq);
            }
        }
        #pragma unroll
        for (int blk = 0; blk < 2; ++blk)
            #pragma unroll
            for (int ch = 0; ch < 3; ++ch)
                sF[blk][ch][lane] = Fv[blk][ch];
        __syncthreads();

        // ---- stage 1: G[u][y] = sum_v c[y][v]*F[u][v]; store transposed [y][u] ----
        #pragma unroll
        for (int blk = 0; blk < 2; ++blk)
            #pragma unroll
            for (int ch = 0; ch < 3; ++ch) {
                const float4 f0 = *(const float4*)&sF[blk][ch][px * 8];
                const float4 f1 = *(const float4*)&sF[blk][ch][px * 8 + 4];
                float g = 0.0f;
                g += cyv[0] * f0.x; g += cyv[1] * f0.y;
                g += cyv[2] * f0.z; g += cyv[3] * f0.w;
                g += cyv[4] * f1.x; g += cyv[5] * f1.y;
                g += cyv[6] * f1.z; g += cyv[7] * f1.w;
                sGt[blk][ch][py * 12 + px] = g;   // (yy=py, uu=px)
            }
        __syncthreads();

        // ---- stage 2 + color-back: two ADJACENT pixels (px, col0/col0+1) of blkL,
        //      float4 LDS reads (pad stride 12 -> conflict-free), float2 stores ----
        float r0[3], r1[3];
        #pragma unroll
        for (int ch = 0; ch < 3; ++ch) {
            const float4 ga0 = *(const float4*)&sGt[blkL][ch][col0 * 12];
            const float4 ga1 = *(const float4*)&sGt[blkL][ch][col0 * 12 + 4];
            const float4 gb0 = *(const float4*)&sGt[blkL][ch][(col0 + 1) * 12];
            const float4 gb1 = *(const float4*)&sGt[blkL][ch][(col0 + 1) * 12 + 4];
            float p0 = 0.0f, p1 = 0.0f;
            p0 += cxu[0] * ga0.x; p0 += cxu[1] * ga0.y;
            p0 += cxu[2] * ga0.z; p0 += cxu[3] * ga0.w;
            p0 += cxu[4] * ga1.x; p0 += cxu[5] * ga1.y;
            p0 += cxu[6] * ga1.z; p0 += cxu[7] * ga1.w;
            p1 += cxu[0] * gb0.x; p1 += cxu[1] * gb0.y;
            p1 += cxu[2] * gb0.z; p1 += cxu[3] * gb0.w;
            p1 += cxu[4] * gb1.x; p1 += cxu[5] * gb1.y;
            p1 += cxu[6] * gb1.z; p1 += cxu[7] * gb1.w;
            r0[ch] = p0 * 0.25f;
            r1[ch] = p1 * 0.25f;
        }
        {
            const float yvA = r0[0] + 128.0f, cbA = r0[1], crA = r0[2];
            const float yvB = r1[0] + 128.0f, cbB = r1[1], crB = r1[2];
            const float roA = yvA + 1.402f * crA;
            const float goA = yvA - 0.344136f * cbA - 0.714136f * crA;
            const float boA = yvA + 1.772f * cbA;
            const float roB = yvB + 1.402f * crB;
            const float goB = yvB - 0.344136f * cbB - 0.714136f * crB;
            const float boB = yvB + 1.772f * cbB;
            const size_t ob = rowbase + 2 * py;   // global cols: blkL*8+col0 == 2*py
            *(float2*)(out + ob) =
                make_float2(clamp255(roA), clamp255(roB));
            *(float2*)(out + ob + PLANE) =
                make_float2(clamp255(goA), clamp255(goB));
            *(float2*)(out + ob + 2 * (size_t)PLANE) =
                make_float2(clamp255(boA), clamp255(boB));
        }
    }
}

extern "C" void kernel_launch(void* const* d_in, const int* in_sizes, int n_in,
                              void* d_out, int out_size, void* d_ws, size_t ws_size,
                              hipStream_t stream) {
    const float* in = (const float*)d_in[0];
    float* out = (float*)d_out;
    jpeg_kernel<<<NWG, 64, 0, stream>>>(in, out);
}

// Round 4
// 162.128 us; speedup vs baseline: 2.3479x; 2.3479x over previous
//
#include <hip/hip_runtime.h>

namespace {

constexpr int BATCH = 16;
constexpr int HH = 512;
constexpr int WW = 512;
constexpr int PLANE = HH * WW;
constexpr int NPAIR = BATCH * (HH / 8) * (WW / 16);  // 32768 block-pairs
constexpr int NWG = 3072;                            // 12 blocks/CU, all co-resident

// ---- numpy-faithful cosine table (DO NOT TOUCH — decision-path numerics) ----
constexpr double PI64 = 3.141592653589793;
constexpr double PI_LO = 1.2246467991473532e-16;
constexpr double PI_HI = (double)((long long)(PI64 * 17592186044416.0)) / 17592186044416.0;
constexpr double PI_MID = PI64 - PI_HI;

constexpr double CD9[9] = {
    1.0,
    0.9807852804032304491,
    0.9238795325112867561,
    0.8314696123025452371,
    0.7071067811865475244,
    0.5555702330196022248,
    0.3826834323650897717,
    0.1950903220161282678,
    0.0};
constexpr double cos_tab(int m) {
    m %= 32;
    double s = 1.0;
    if (m > 16) m = 32 - m;
    if (m > 8) { s = -1.0; m = 16 - m; }
    return s * CD9[m];
}
constexpr double sin_tab(int m) { return cos_tab(m + 24); }

constexpr double cx64(int K) {
    float Kf = (float)K;
    float p32 = (float)PI64;
    float t32 = Kf * p32;
    double F = (double)t32;
    double E = ((F - (double)K * PI_HI) - (double)K * PI_MID) - (double)K * PI_LO;
    double r = E / 16.0;
    double C = cos_tab(K), S = sin_tab(K);
    double cr = 1.0 - 0.5 * r * r;
    double sr = r - (r * r * r) / 6.0;
    return C * cr - S * sr;
}
constexpr float cx32(int x, int u) { return (float)cx64((2 * x + 1) * u); }

struct C32A { float c[64]; };
constexpr C32A make_c32f() {
    C32A a{};
    for (int x = 0; x < 8; ++x)
        for (int u = 0; u < 8; ++u)
            a.c[x * 8 + u] = cx32(x, u);
    return a;
}
constexpr C32A C32F = make_c32f();

constexpr float YQ[64] = {
    16, 11, 10, 16, 24, 40, 51, 61,
    12, 12, 14, 19, 26, 58, 60, 55,
    14, 13, 16, 24, 40, 57, 69, 56,
    14, 17, 22, 29, 51, 87, 80, 62,
    18, 22, 37, 56, 68, 109, 103, 77,
    24, 35, 55, 64, 81, 104, 113, 92,
    49, 64, 78, 87, 103, 121, 120, 101,
    72, 92, 95, 98, 112, 100, 103, 99};

constexpr float CQ[64] = {
    17, 18, 24, 47, 99, 99, 99, 99,
    18, 21, 26, 66, 99, 99, 99, 99,
    24, 26, 56, 99, 99, 99, 99, 99,
    47, 66, 99, 99, 99, 99, 99, 99,
    99, 99, 99, 99, 99, 99, 99, 99,
    99, 99, 99, 99, 99, 99, 99, 99,
    99, 99, 99, 99, 99, 99, 99, 99,
    99, 99, 99, 99, 99, 99, 99, 99};

constexpr float AL32 = (float)0.7071067811865475244;

} // namespace

// fp64 color transform — bit-identical (decision path).
__device__ __forceinline__ void color_f64(float Rf, float Gf, float Bf,
                                          double& yv, double& cbv, double& crv) {
    const double rv = ((double)Rf + 1.0) * 127.5;
    const double gv = ((double)Gf + 1.0) * 127.5;
    const double bv = ((double)Bf + 1.0) * 127.5;
    yv = ((double)0.299f * rv + (double)0.587f * gv) + (double)0.114f * bv;
    yv = yv - 128.0;
    cbv = ((double)-0.168736f * rv + (double)-0.331264f * gv) + (double)0.5f * bv;
    cbv = (cbv + 128.0) - 128.0;
    crv = ((double)0.5f * rv + (double)-0.418688f * gv) + (double)-0.081312f * bv;
    crv = (crv + 128.0) - 128.0;
}

__device__ __forceinline__ float clamp255(float x) {
    return fminf(fmaxf(x, 0.0f), 255.0f) * (1.0f / 255.0f);
}

// One wave = one PAIR of horizontally adjacent 8x8 blocks per iteration.
__global__ __launch_bounds__(64, 3) void jpeg_kernel(const float* __restrict__ in,
                                                     float* __restrict__ out) {
    __shared__ __align__(16) double sYd[2][3][64];  // pair x channel x spatial (f64)
    __shared__ __align__(16) float  sF [2][3][64];  // dequantized*alpha coefficients [u][v]
    __shared__ __align__(16) float  sGt[2][3][96];  // idct stage-1, TRANSPOSED [y][u], stride 12

    const int lane = threadIdx.x;     // 0..63
    const int px = lane >> 3;         // row within block / u-index for DCT
    const int py = lane & 7;          // col index        / v-index for DCT

    // ---- one-time per-lane constants ----
    // T[uv][x*8+y] = (double)( fl32( c[x][u] * c[y][v] ) )  — rank-1 remat,
    // bit-identical to the constexpr f64 table of prior rounds.
    float Tf[64];
    {
        float cu[8], cv[8];
        #pragma unroll
        for (int k = 0; k < 8; ++k) {
            cu[k] = C32F.c[k * 8 + px];   // c[x][u], u = lane>>3
            cv[k] = C32F.c[k * 8 + py];   // c[y][v], v = lane&7
        }
        #pragma unroll
        for (int x = 0; x < 8; ++x)
            #pragma unroll
            for (int y = 0; y < 8; ++y)
                Tf[x * 8 + y] = cu[x] * cv[y];  // exact f32 mul == constexpr table
    }
    // idct cosine rows (registers)
    float cyv[8], cxu[8];
    #pragma unroll
    for (int k = 0; k < 8; ++k) {
        cyv[k] = C32F.c[py * 8 + k];      // stage-1 row (yy = lane&7)
        cxu[k] = C32F.c[px * 8 + k];      // stage-2 row (px = lane>>3)
    }

    // quant constants, minimal register footprint; f64 values re-derived
    // per use EXACTLY as the old QD table computed them:
    //   qty = (double)YQ[i]; dqy = (double)YQ[i] * (double)aa; m = (double)(aa*0.25f)
    const float yqf  = YQ[lane];
    const float cqf  = CQ[lane];
    const float aa32 = (px == 0 ? AL32 : 1.0f) * (py == 0 ? AL32 : 1.0f);
    const double aaD = (double)aa32;
    const double mQ  = (double)(aa32 * 0.25f);

    const int blkL = py >> 2;         // which block this lane's pixel-pair is in
    const int col0 = (py & 3) * 2;    // first of two adjacent columns in that block

    #pragma unroll 1
    for (int P = blockIdx.x; P < NPAIR; P += NWG) {
        const int b = P >> 11;              // image (2048 pairs per image)
        const int p2 = P & 2047;
        const int by = p2 >> 5;             // block row (64 rows)
        const int pbx = p2 & 31;            // pair col (32 pairs per row)
        const size_t rowbase = (size_t)b * 3 * PLANE + (size_t)(by * 8 + px) * WW
                             + (size_t)(pbx * 16);

        // ---- full-cache-line loads: float2 per lane per channel ----
        const float2 Rp = *(const float2*)(in + rowbase + 2 * py);
        const float2 Gp = *(const float2*)(in + rowbase + PLANE + 2 * py);
        const float2 Bp = *(const float2*)(in + rowbase + 2 * (size_t)PLANE + 2 * py);

        __syncthreads();   // prior iteration's DCT dots are done with sYd

        {
            double y0, cb0, cr0, y1, cb1, cr1;
            color_f64(Rp.x, Gp.x, Bp.x, y0, cb0, cr0);
            color_f64(Rp.y, Gp.y, Bp.y, y1, cb1, cr1);
            const int si = px * 8 + col0;
            *(double2*)&sYd[blkL][0][si] = make_double2(y0, y1);
            *(double2*)&sYd[blkL][1][si] = make_double2(cb0, cb1);
            *(double2*)&sYd[blkL][2][si] = make_double2(cr0, cr1);
        }
        __syncthreads();

        // ---- 6 independent fp64 DCT dots. FMA chain structure/order
        //      bit-identical to prior verified rounds. Tf is LAUNDERED per dot
        //      (zero-cost asm) so LICM/GVN cannot hoist the 64 f64 widenings
        //      out of the loop (that hoist = 128 persistent regs = the R2 spill).
        double S[2][3];
        #pragma unroll
        for (int blk = 0; blk < 2; ++blk) {
            #pragma unroll
            for (int ch = 0; ch < 3; ++ch) {
                #pragma unroll
                for (int i = 0; i < 64; ++i)
                    asm volatile("" : "+v"(Tf[i]));   // fresh defs: no LICM/CSE

                const double2* __restrict__ Y2 = (const double2*)&sYd[blk][ch][0];
                double a0 = 0.0, a1 = 0.0, a2 = 0.0, a3 = 0.0;
                #pragma unroll
                for (int g = 0; g < 4; ++g) {
                    __builtin_amdgcn_sched_barrier(0);   // cap in-flight LDS loads
                    const int j0 = 2 * g, j1 = 2 * g + 1;
                    const double2 p0 = Y2[j0],      q0 = Y2[j1];
                    const double2 p1 = Y2[j0 + 8],  q1 = Y2[j1 + 8];
                    const double2 p2d = Y2[j0 + 16], q2 = Y2[j1 + 16];
                    const double2 p3 = Y2[j0 + 24], q3 = Y2[j1 + 24];
                    a0 = __builtin_fma((double)Tf[2 * j0],      p0.x,  a0);
                    a0 = __builtin_fma((double)Tf[2 * j0 + 1],  p0.y,  a0);
                    a0 = __builtin_fma((double)Tf[2 * j1],      q0.x,  a0);
                    a0 = __builtin_fma((double)Tf[2 * j1 + 1],  q0.y,  a0);
                    a1 = __builtin_fma((double)Tf[2 * j0 + 16], p1.x,  a1);
                    a1 = __builtin_fma((double)Tf[2 * j0 + 17], p1.y,  a1);
                    a1 = __builtin_fma((double)Tf[2 * j1 + 16], q1.x,  a1);
                    a1 = __builtin_fma((double)Tf[2 * j1 + 17], q1.y,  a1);
                    a2 = __builtin_fma((double)Tf[2 * j0 + 32], p2d.x, a2);
                    a2 = __builtin_fma((double)Tf[2 * j0 + 33], p2d.y, a2);
                    a2 = __builtin_fma((double)Tf[2 * j1 + 32], q2.x,  a2);
                    a2 = __builtin_fma((double)Tf[2 * j1 + 33], q2.y,  a2);
                    a3 = __builtin_fma((double)Tf[2 * j0 + 48], p3.x,  a3);
                    a3 = __builtin_fma((double)Tf[2 * j0 + 49], p3.y,  a3);
                    a3 = __builtin_fma((double)Tf[2 * j1 + 48], q3.x,  a3);
                    a3 = __builtin_fma((double)Tf[2 * j1 + 49], q3.y,  a3);
                }
                S[blk][ch] = (a0 + a1) + (a2 + a3);
            }
        }
        __builtin_amdgcn_sched_barrier(0);

        // ---- diff-round quant (per-value op sequence identical to prior rounds;
        //      the 6 values are independent, so batching them adds divide ILP) ----
        float Fv[2][3];
        #pragma unroll
        for (int blk = 0; blk < 2; ++blk) {
            #pragma unroll
            for (int ch = 0; ch < 3; ++ch) {
                const double qtd = (ch == 0) ? (double)yqf : (double)cqf;
                const double dq  = qtd * aaD;
                const double f = (mQ * S[blk][ch]) / qtd;   // true f64 divide
                const double rr = __builtin_rint(f);        // half-to-even
                const double d = f - rr;
                Fv[blk][ch] = (float)((rr + (d * d) * d) * dq);
            }
        }
        #pragma unroll
        for (int blk = 0; blk < 2; ++blk)
            #pragma unroll
            for (int ch = 0; ch < 3; ++ch)
                sF[blk][ch][lane] = Fv[blk][ch];
        __syncthreads();

        // ---- stage 1: G[u][y] = sum_v c[y][v]*F[u][v]; store transposed [y][u] ----
        #pragma unroll
        for (int blk = 0; blk < 2; ++blk)
            #pragma unroll
            for (int ch = 0; ch < 3; ++ch) {
                const float4 f0 = *(const float4*)&sF[blk][ch][px * 8];
                const float4 f1 = *(const float4*)&sF[blk][ch][px * 8 + 4];
                float g = 0.0f;
                g += cyv[0] * f0.x; g += cyv[1] * f0.y;
                g += cyv[2] * f0.z; g += cyv[3] * f0.w;
                g += cyv[4] * f1.x; g += cyv[5] * f1.y;
                g += cyv[6] * f1.z; g += cyv[7] * f1.w;
                sGt[blk][ch][py * 12 + px] = g;   // (yy=py, uu=px)
            }
        __syncthreads();

        // ---- stage 2 + color-back: two ADJACENT pixels (px, col0/col0+1) of blkL ----
        float r0[3], r1[3];
        #pragma unroll
        for (int ch = 0; ch < 3; ++ch) {
            const float4 ga0 = *(const float4*)&sGt[blkL][ch][col0 * 12];
            const float4 ga1 = *(const float4*)&sGt[blkL][ch][col0 * 12 + 4];
            const float4 gb0 = *(const float4*)&sGt[blkL][ch][(col0 + 1) * 12];
            const float4 gb1 = *(const float4*)&sGt[blkL][ch][(col0 + 1) * 12 + 4];
            float p0 = 0.0f, p1 = 0.0f;
            p0 += cxu[0] * ga0.x; p0 += cxu[1] * ga0.y;
            p0 += cxu[2] * ga0.z; p0 += cxu[3] * ga0.w;
            p0 += cxu[4] * ga1.x; p0 += cxu[5] * ga1.y;
            p0 += cxu[6] * ga1.z; p0 += cxu[7] * ga1.w;
            p1 += cxu[0] * gb0.x; p1 += cxu[1] * gb0.y;
            p1 += cxu[2] * gb0.z; p1 += cxu[3] * gb0.w;
            p1 += cxu[4] * gb1.x; p1 += cxu[5] * gb1.y;
            p1 += cxu[6] * gb1.z; p1 += cxu[7] * gb1.w;
            r0[ch] = p0 * 0.25f;
            r1[ch] = p1 * 0.25f;
        }
        {
            const float yvA = r0[0] + 128.0f, cbA = r0[1], crA = r0[2];
            const float yvB = r1[0] + 128.0f, cbB = r1[1], crB = r1[2];
            const float roA = yvA + 1.402f * crA;
            const float goA = yvA - 0.344136f * cbA - 0.714136f * crA;
            const float boA = yvA + 1.772f * cbA;
            const float roB = yvB + 1.402f * crB;
            const float goB = yvB - 0.344136f * cbB - 0.714136f * crB;
            const float boB = yvB + 1.772f * cbB;
            const size_t ob = rowbase + 2 * py;   // global cols: blkL*8+col0 == 2*py
            *(float2*)(out + ob) =
                make_float2(clamp255(roA), clamp255(roB));
            *(float2*)(out + ob + PLANE) =
                make_float2(clamp255(goA), clamp255(goB));
            *(float2*)(out + ob + 2 * (size_t)PLANE) =
                make_float2(clamp255(boA), clamp255(boB));
        }
    }
}

extern "C" void kernel_launch(void* const* d_in, const int* in_sizes, int n_in,
                              void* d_out, int out_size, void* d_ws, size_t ws_size,
                              hipStream_t stream) {
    const float* in = (const float*)d_in[0];
    float* out = (float*)d_out;
    jpeg_kernel<<<NWG, 64, 0, stream>>>(in, out);
}

// Round 5
// 154.187 us; speedup vs baseline: 2.4689x; 1.0515x over previous
//
#include <hip/hip_runtime.h>

namespace {

constexpr int BATCH = 16;
constexpr int HH = 512;
constexpr int WW = 512;
constexpr int PLANE = HH * WW;
constexpr int NPAIR = BATCH * (HH / 8) * (WW / 16);  // 32768 block-pairs
constexpr int NWG = 3072;                            // 12 blocks/CU, all co-resident

// ---- numpy-faithful cosine table (DO NOT TOUCH — decision-path numerics) ----
constexpr double PI64 = 3.141592653589793;
constexpr double PI_LO = 1.2246467991473532e-16;
constexpr double PI_HI = (double)((long long)(PI64 * 17592186044416.0)) / 17592186044416.0;
constexpr double PI_MID = PI64 - PI_HI;

constexpr double CD9[9] = {
    1.0,
    0.9807852804032304491,
    0.9238795325112867561,
    0.8314696123025452371,
    0.7071067811865475244,
    0.5555702330196022248,
    0.3826834323650897717,
    0.1950903220161282678,
    0.0};
constexpr double cos_tab(int m) {
    m %= 32;
    double s = 1.0;
    if (m > 16) m = 32 - m;
    if (m > 8) { s = -1.0; m = 16 - m; }
    return s * CD9[m];
}
constexpr double sin_tab(int m) { return cos_tab(m + 24); }

constexpr double cx64(int K) {
    float Kf = (float)K;
    float p32 = (float)PI64;
    float t32 = Kf * p32;
    double F = (double)t32;
    double E = ((F - (double)K * PI_HI) - (double)K * PI_MID) - (double)K * PI_LO;
    double r = E / 16.0;
    double C = cos_tab(K), S = sin_tab(K);
    double cr = 1.0 - 0.5 * r * r;
    double sr = r - (r * r * r) / 6.0;
    return C * cr - S * sr;
}
constexpr float cx32(int x, int u) { return (float)cx64((2 * x + 1) * u); }

struct C32A { float c[64]; };
constexpr C32A make_c32f() {
    C32A a{};
    for (int x = 0; x < 8; ++x)
        for (int u = 0; u < 8; ++u)
            a.c[x * 8 + u] = cx32(x, u);
    return a;
}
constexpr C32A C32F = make_c32f();

constexpr float YQ[64] = {
    16, 11, 10, 16, 24, 40, 51, 61,
    12, 12, 14, 19, 26, 58, 60, 55,
    14, 13, 16, 24, 40, 57, 69, 56,
    14, 17, 22, 29, 51, 87, 80, 62,
    18, 22, 37, 56, 68, 109, 103, 77,
    24, 35, 55, 64, 81, 104, 113, 92,
    49, 64, 78, 87, 103, 121, 120, 101,
    72, 92, 95, 98, 112, 100, 103, 99};

constexpr float CQ[64] = {
    17, 18, 24, 47, 99, 99, 99, 99,
    18, 21, 26, 66, 99, 99, 99, 99,
    24, 26, 56, 99, 99, 99, 99, 99,
    47, 66, 99, 99, 99, 99, 99, 99,
    99, 99, 99, 99, 99, 99, 99, 99,
    99, 99, 99, 99, 99, 99, 99, 99,
    99, 99, 99, 99, 99, 99, 99, 99,
    99, 99, 99, 99, 99, 99, 99, 99};

constexpr float AL32 = (float)0.7071067811865475244;

} // namespace

// fp64 color transform — bit-identical (decision path).
__device__ __forceinline__ void color_f64(float Rf, float Gf, float Bf,
                                          double& yv, double& cbv, double& crv) {
    const double rv = ((double)Rf + 1.0) * 127.5;
    const double gv = ((double)Gf + 1.0) * 127.5;
    const double bv = ((double)Bf + 1.0) * 127.5;
    yv = ((double)0.299f * rv + (double)0.587f * gv) + (double)0.114f * bv;
    yv = yv - 128.0;
    cbv = ((double)-0.168736f * rv + (double)-0.331264f * gv) + (double)0.5f * bv;
    cbv = (cbv + 128.0) - 128.0;
    crv = ((double)0.5f * rv + (double)-0.418688f * gv) + (double)-0.081312f * bv;
    crv = (crv + 128.0) - 128.0;
}

__device__ __forceinline__ float clamp255(float x) {
    return fminf(fmaxf(x, 0.0f), 255.0f) * (1.0f / 255.0f);
}

// One wave = one PAIR of horizontally adjacent 8x8 blocks per iteration.
__global__ __launch_bounds__(64, 3) void jpeg_kernel(const float* __restrict__ in,
                                                     float* __restrict__ out) {
    __shared__ __align__(16) double sYd[2][3][64];  // pair x channel x spatial (f64)
    __shared__ __align__(16) float  sF [2][3][64];  // dequantized*alpha coefficients [u][v]
    __shared__ __align__(16) float  sGt[2][3][96];  // idct stage-1, TRANSPOSED [y][u], stride 12
    __shared__ __align__(16) float  sC[64];         // fp32 cosines c[x][u] (frees 16 VGPRs)

    const int lane = threadIdx.x;     // 0..63
    const int px = lane >> 3;         // row within block / u-index for DCT
    const int py = lane & 7;          // col index        / v-index for DCT

    sC[lane] = C32F.c[lane];

    // ---- one-time per-lane constants ----
    // T[uv][x*8+y] = (double)( fl32( c[x][u] * c[y][v] ) )  — rank-1 remat,
    // bit-identical to the constexpr f64 table of prior rounds.
    float Tf[64];
    {
        float cu[8], cv[8];
        #pragma unroll
        for (int k = 0; k < 8; ++k) {
            cu[k] = C32F.c[k * 8 + px];   // c[x][u], u = lane>>3
            cv[k] = C32F.c[k * 8 + py];   // c[y][v], v = lane&7
        }
        #pragma unroll
        for (int x = 0; x < 8; ++x)
            #pragma unroll
            for (int y = 0; y < 8; ++y)
                Tf[x * 8 + y] = cu[x] * cv[y];  // exact f32 mul == constexpr table
    }

    // quant constants, minimal register footprint; f64 values re-derived
    // per use EXACTLY as the old QD table computed them.
    const float yqf  = YQ[lane];
    const float cqf  = CQ[lane];
    const float aa32 = (px == 0 ? AL32 : 1.0f) * (py == 0 ? AL32 : 1.0f);
    const double aaD = (double)aa32;
    const double mQ  = (double)(aa32 * 0.25f);

    const int blkL = py >> 2;         // which block this lane's pixel-pair is in
    const int col0 = (py & 3) * 2;    // first of two adjacent columns in that block

    #pragma unroll 1
    for (int P = blockIdx.x; P < NPAIR; P += NWG) {
        const int b = P >> 11;              // image (2048 pairs per image)
        const int p2 = P & 2047;
        const int by = p2 >> 5;             // block row (64 rows)
        const int pbx = p2 & 31;            // pair col (32 pairs per row)
        const size_t rowbase = (size_t)b * 3 * PLANE + (size_t)(by * 8 + px) * WW
                             + (size_t)(pbx * 16);

        // ---- full-cache-line loads: float2 per lane per channel ----
        const float2 Rp = *(const float2*)(in + rowbase + 2 * py);
        const float2 Gp = *(const float2*)(in + rowbase + PLANE + 2 * py);
        const float2 Bp = *(const float2*)(in + rowbase + 2 * (size_t)PLANE + 2 * py);

        __syncthreads();   // prior iteration's DCT dots are done with sYd

        {
            double y0, cb0, cr0, y1, cb1, cr1;
            color_f64(Rp.x, Gp.x, Bp.x, y0, cb0, cr0);
            color_f64(Rp.y, Gp.y, Bp.y, y1, cb1, cr1);
            const int si = px * 8 + col0;
            *(double2*)&sYd[blkL][0][si] = make_double2(y0, y1);
            *(double2*)&sYd[blkL][1][si] = make_double2(cb0, cb1);
            *(double2*)&sYd[blkL][2][si] = make_double2(cr0, cr1);
        }
        __syncthreads();

        // ---- 6 fp64 DCT dots, ch-outer so each f64 widening of Tf serves BOTH
        //      blocks (192 cvt/pair instead of 384). Per-accumulator FMA order
        //      is bit-identical to prior verified rounds: a0 receives
        //      Tf[0],Tf[1],...,Tf[15] against Y[0..15] in sequence, etc.
        //      Tf is LAUNDERED per ch (zero-cost asm) so LICM/GVN cannot hoist
        //      the widenings out of the loop (that hoist = the R2 spill).
        double S[2][3];
        #pragma unroll
        for (int ch = 0; ch < 3; ++ch) {
            #pragma unroll
            for (int i = 0; i < 64; ++i)
                asm volatile("" : "+v"(Tf[i]));   // fresh defs: no LICM/CSE

            const double2* __restrict__ YA = (const double2*)&sYd[0][ch][0];
            const double2* __restrict__ YB = (const double2*)&sYd[1][ch][0];
            double a00 = 0.0, a01 = 0.0, a02 = 0.0, a03 = 0.0;
            double a10 = 0.0, a11 = 0.0, a12 = 0.0, a13 = 0.0;
            #pragma unroll
            for (int j = 0; j < 8; ++j) {
                __builtin_amdgcn_sched_barrier(0);   // cap in-flight pressure
                const double t0 = (double)Tf[2 * j];
                const double t1 = (double)Tf[2 * j + 1];
                const double t2 = (double)Tf[2 * j + 16];
                const double t3 = (double)Tf[2 * j + 17];
                const double t4 = (double)Tf[2 * j + 32];
                const double t5 = (double)Tf[2 * j + 33];
                const double t6 = (double)Tf[2 * j + 48];
                const double t7 = (double)Tf[2 * j + 49];
                {
                    const double2 u0 = YA[j];
                    const double2 u1 = YA[j + 8];
                    const double2 u2 = YA[j + 16];
                    const double2 u3 = YA[j + 24];
                    a00 = __builtin_fma(t0, u0.x, a00);
                    a00 = __builtin_fma(t1, u0.y, a00);
                    a01 = __builtin_fma(t2, u1.x, a01);
                    a01 = __builtin_fma(t3, u1.y, a01);
                    a02 = __builtin_fma(t4, u2.x, a02);
                    a02 = __builtin_fma(t5, u2.y, a02);
                    a03 = __builtin_fma(t6, u3.x, a03);
                    a03 = __builtin_fma(t7, u3.y, a03);
                }
                {
                    const double2 w0 = YB[j];
                    const double2 w1 = YB[j + 8];
                    const double2 w2 = YB[j + 16];
                    const double2 w3 = YB[j + 24];
                    a10 = __builtin_fma(t0, w0.x, a10);
                    a10 = __builtin_fma(t1, w0.y, a10);
                    a11 = __builtin_fma(t2, w1.x, a11);
                    a11 = __builtin_fma(t3, w1.y, a11);
                    a12 = __builtin_fma(t4, w2.x, a12);
                    a12 = __builtin_fma(t5, w2.y, a12);
                    a13 = __builtin_fma(t6, w3.x, a13);
                    a13 = __builtin_fma(t7, w3.y, a13);
                }
            }
            S[0][ch] = (a00 + a01) + (a02 + a03);
            S[1][ch] = (a10 + a11) + (a12 + a13);
        }
        __builtin_amdgcn_sched_barrier(0);

        // ---- diff-round quant (per-value op sequence identical to prior rounds;
        //      the 6 values are independent, batching adds divide ILP) ----
        float Fv[2][3];
        #pragma unroll
        for (int blk = 0; blk < 2; ++blk) {
            #pragma unroll
            for (int ch = 0; ch < 3; ++ch) {
                const double qtd = (ch == 0) ? (double)yqf : (double)cqf;
                const double dq  = qtd * aaD;
                const double f = (mQ * S[blk][ch]) / qtd;   // true f64 divide
                const double rr = __builtin_rint(f);        // half-to-even
                const double d = f - rr;
                Fv[blk][ch] = (float)((rr + (d * d) * d) * dq);
            }
        }
        #pragma unroll
        for (int blk = 0; blk < 2; ++blk)
            #pragma unroll
            for (int ch = 0; ch < 3; ++ch)
                sF[blk][ch][lane] = Fv[blk][ch];
        __syncthreads();

        // ---- stage 1: G[u][y] = sum_v c[y][v]*F[u][v]; store transposed [y][u].
        //      cosine row read from sC per pair (transient, frees persistent regs)
        {
            const float4 cy0 = *(const float4*)&sC[py * 8];
            const float4 cy1 = *(const float4*)&sC[py * 8 + 4];
            #pragma unroll
            for (int blk = 0; blk < 2; ++blk)
                #pragma unroll
                for (int ch = 0; ch < 3; ++ch) {
                    const float4 f0 = *(const float4*)&sF[blk][ch][px * 8];
                    const float4 f1 = *(const float4*)&sF[blk][ch][px * 8 + 4];
                    float g = 0.0f;
                    g += cy0.x * f0.x; g += cy0.y * f0.y;
                    g += cy0.z * f0.z; g += cy0.w * f0.w;
                    g += cy1.x * f1.x; g += cy1.y * f1.y;
                    g += cy1.z * f1.z; g += cy1.w * f1.w;
                    sGt[blk][ch][py * 12 + px] = g;   // (yy=py, uu=px)
                }
        }
        __syncthreads();

        // ---- stage 2 + color-back: two ADJACENT pixels (px, col0/col0+1) of blkL ----
        float r0[3], r1[3];
        {
            const float4 cx0 = *(const float4*)&sC[px * 8];
            const float4 cx1 = *(const float4*)&sC[px * 8 + 4];
            #pragma unroll
            for (int ch = 0; ch < 3; ++ch) {
                const float4 ga0 = *(const float4*)&sGt[blkL][ch][col0 * 12];
                const float4 ga1 = *(const float4*)&sGt[blkL][ch][col0 * 12 + 4];
                const float4 gb0 = *(const float4*)&sGt[blkL][ch][(col0 + 1) * 12];
                const float4 gb1 = *(const float4*)&sGt[blkL][ch][(col0 + 1) * 12 + 4];
                float p0 = 0.0f, p1 = 0.0f;
                p0 += cx0.x * ga0.x; p0 += cx0.y * ga0.y;
                p0 += cx0.z * ga0.z; p0 += cx0.w * ga0.w;
                p0 += cx1.x * ga1.x; p0 += cx1.y * ga1.y;
                p0 += cx1.z * ga1.z; p0 += cx1.w * ga1.w;
                p1 += cx0.x * gb0.x; p1 += cx0.y * gb0.y;
                p1 += cx0.z * gb0.z; p1 += cx0.w * gb0.w;
                p1 += cx1.x * gb1.x; p1 += cx1.y * gb1.y;
                p1 += cx1.z * gb1.z; p1 += cx1.w * gb1.w;
                r0[ch] = p0 * 0.25f;
                r1[ch] = p1 * 0.25f;
            }
        }
        {
            const float yvA = r0[0] + 128.0f, cbA = r0[1], crA = r0[2];
            const float yvB = r1[0] + 128.0f, cbB = r1[1], crB = r1[2];
            const float roA = yvA + 1.402f * crA;
            const float goA = yvA - 0.344136f * cbA - 0.714136f * crA;
            const float boA = yvA + 1.772f * cbA;
            const float roB = yvB + 1.402f * crB;
            const float goB = yvB - 0.344136f * cbB - 0.714136f * crB;
            const float boB = yvB + 1.772f * cbB;
            const size_t ob = rowbase + 2 * py;   // global cols: blkL*8+col0 == 2*py
            *(float2*)(out + ob) =
                make_float2(clamp255(roA), clamp255(roB));
            *(float2*)(out + ob + PLANE) =
                make_float2(clamp255(goA), clamp255(goB));
            *(float2*)(out + ob + 2 * (size_t)PLANE) =
                make_float2(clamp255(boA), clamp255(boB));
        }
    }
}

extern "C" void kernel_launch(void* const* d_in, const int* in_sizes, int n_in,
                              void* d_out, int out_size, void* d_ws, size_t ws_size,
                              hipStream_t stream) {
    const float* in = (const float*)d_in[0];
    float* out = (float*)d_out;
    jpeg_kernel<<<NWG, 64, 0, stream>>>(in, out);
}

// Round 6
// 151.017 us; speedup vs baseline: 2.5207x; 1.0210x over previous
//
#include <hip/hip_runtime.h>

namespace {

constexpr int BATCH = 16;
constexpr int HH = 512;
constexpr int WW = 512;
constexpr int PLANE = HH * WW;
constexpr int NPAIR = BATCH * (HH / 8) * (WW / 16);  // 32768 block-pairs
constexpr int NWG = 8192;                            // ITERS=4, fine-grained balance

// ---- numpy-faithful cosine table (DO NOT TOUCH — decision-path numerics) ----
constexpr double PI64 = 3.141592653589793;
constexpr double PI_LO = 1.2246467991473532e-16;
constexpr double PI_HI = (double)((long long)(PI64 * 17592186044416.0)) / 17592186044416.0;
constexpr double PI_MID = PI64 - PI_HI;

constexpr double CD9[9] = {
    1.0,
    0.9807852804032304491,
    0.9238795325112867561,
    0.8314696123025452371,
    0.7071067811865475244,
    0.5555702330196022248,
    0.3826834323650897717,
    0.1950903220161282678,
    0.0};
constexpr double cos_tab(int m) {
    m %= 32;
    double s = 1.0;
    if (m > 16) m = 32 - m;
    if (m > 8) { s = -1.0; m = 16 - m; }
    return s * CD9[m];
}
constexpr double sin_tab(int m) { return cos_tab(m + 24); }

constexpr double cx64(int K) {
    float Kf = (float)K;
    float p32 = (float)PI64;
    float t32 = Kf * p32;
    double F = (double)t32;
    double E = ((F - (double)K * PI_HI) - (double)K * PI_MID) - (double)K * PI_LO;
    double r = E / 16.0;
    double C = cos_tab(K), S = sin_tab(K);
    double cr = 1.0 - 0.5 * r * r;
    double sr = r - (r * r * r) / 6.0;
    return C * cr - S * sr;
}
constexpr float cx32(int x, int u) { return (float)cx64((2 * x + 1) * u); }

struct C32A { float c[64]; };
constexpr C32A make_c32f() {
    C32A a{};
    for (int x = 0; x < 8; ++x)
        for (int u = 0; u < 8; ++u)
            a.c[x * 8 + u] = cx32(x, u);
    return a;
}
constexpr C32A C32F = make_c32f();

constexpr float YQ[64] = {
    16, 11, 10, 16, 24, 40, 51, 61,
    12, 12, 14, 19, 26, 58, 60, 55,
    14, 13, 16, 24, 40, 57, 69, 56,
    14, 17, 22, 29, 51, 87, 80, 62,
    18, 22, 37, 56, 68, 109, 103, 77,
    24, 35, 55, 64, 81, 104, 113, 92,
    49, 64, 78, 87, 103, 121, 120, 101,
    72, 92, 95, 98, 112, 100, 103, 99};

constexpr float CQ[64] = {
    17, 18, 24, 47, 99, 99, 99, 99,
    18, 21, 26, 66, 99, 99, 99, 99,
    24, 26, 56, 99, 99, 99, 99, 99,
    47, 66, 99, 99, 99, 99, 99, 99,
    99, 99, 99, 99, 99, 99, 99, 99,
    99, 99, 99, 99, 99, 99, 99, 99,
    99, 99, 99, 99, 99, 99, 99, 99,
    99, 99, 99, 99, 99, 99, 99, 99};

constexpr float AL32 = (float)0.7071067811865475244;

} // namespace

// fp64 color transform — bit-identical (decision path).
__device__ __forceinline__ void color_f64(float Rf, float Gf, float Bf,
                                          double& yv, double& cbv, double& crv) {
    const double rv = ((double)Rf + 1.0) * 127.5;
    const double gv = ((double)Gf + 1.0) * 127.5;
    const double bv = ((double)Bf + 1.0) * 127.5;
    yv = ((double)0.299f * rv + (double)0.587f * gv) + (double)0.114f * bv;
    yv = yv - 128.0;
    cbv = ((double)-0.168736f * rv + (double)-0.331264f * gv) + (double)0.5f * bv;
    cbv = (cbv + 128.0) - 128.0;
    crv = ((double)0.5f * rv + (double)-0.418688f * gv) + (double)-0.081312f * bv;
    crv = (crv + 128.0) - 128.0;
}

__device__ __forceinline__ float clamp255(float x) {
    return fminf(fmaxf(x, 0.0f), 255.0f) * (1.0f / 255.0f);
}

// One wave = one PAIR of horizontally adjacent 8x8 blocks per iteration.
// Rank-1 DCT coefficients remat'd per use: t = (double)(fl32(cu[x]*cv[y]))
// == the old constexpr f64 table entry, but zero persistent table storage.
__global__ __launch_bounds__(64, 4) void jpeg_kernel(const float* __restrict__ in,
                                                     float* __restrict__ out) {
    __shared__ __align__(16) double sYd[2][3][64];  // pair x channel x spatial (f64)
    __shared__ __align__(16) float  sF [2][3][64];  // dequantized*alpha coefficients [u][v]
    __shared__ __align__(16) float  sGt[2][3][96];  // idct stage-1, TRANSPOSED [y][u], stride 12
    __shared__ __align__(16) float  sC[64];         // fp32 cosines c[x][u]

    const int lane = threadIdx.x;     // 0..63
    const int px = lane >> 3;         // row within block / u-index for DCT
    const int py = lane & 7;          // col index        / v-index for DCT

    sC[lane] = C32F.c[lane];

    // rank-1 factors of this lane's T row: T[x*8+y] = cu[x]*cv[y]  (16 regs)
    float cu[8], cv[8];
    #pragma unroll
    for (int k = 0; k < 8; ++k) {
        cu[k] = C32F.c[k * 8 + px];   // c[x][u], u = lane>>3
        cv[k] = C32F.c[k * 8 + py];   // c[y][v], v = lane&7
    }

    // quant constants, minimal footprint; f64 values re-derived per use
    // EXACTLY as the old QD table computed them.
    const float yqf  = YQ[lane];
    const float cqf  = CQ[lane];
    const float aa32 = (px == 0 ? AL32 : 1.0f) * (py == 0 ? AL32 : 1.0f);
    const double aaD = (double)aa32;
    const double mQ  = (double)(aa32 * 0.25f);

    const int blkL = py >> 2;         // which block this lane's pixel-pair is in
    const int col0 = (py & 3) * 2;    // first of two adjacent columns in that block

    #pragma unroll 1
    for (int P = blockIdx.x; P < NPAIR; P += NWG) {
        const int b = P >> 11;              // image (2048 pairs per image)
        const int p2 = P & 2047;
        const int by = p2 >> 5;             // block row (64 rows)
        const int pbx = p2 & 31;            // pair col (32 pairs per row)
        const size_t rowbase = (size_t)b * 3 * PLANE + (size_t)(by * 8 + px) * WW
                             + (size_t)(pbx * 16);

        // ---- full-cache-line loads: float2 per lane per channel ----
        const float2 Rp = *(const float2*)(in + rowbase + 2 * py);
        const float2 Gp = *(const float2*)(in + rowbase + PLANE + 2 * py);
        const float2 Bp = *(const float2*)(in + rowbase + 2 * (size_t)PLANE + 2 * py);

        __syncthreads();   // prior iteration's DCT dots are done with sYd

        {
            double y0, cb0, cr0, y1, cb1, cr1;
            color_f64(Rp.x, Gp.x, Bp.x, y0, cb0, cr0);
            color_f64(Rp.y, Gp.y, Bp.y, y1, cb1, cr1);
            const int si = px * 8 + col0;
            *(double2*)&sYd[blkL][0][si] = make_double2(y0, y1);
            *(double2*)&sYd[blkL][1][si] = make_double2(cb0, cb1);
            *(double2*)&sYd[blkL][2][si] = make_double2(cr0, cr1);
        }
        __syncthreads();

        // ---- 6 fp64 DCT dots, j-OUTER / ch-INNER: each f64 widening of a
        //      T element serves all 6 dots (64 cvt + 64 f32 mul per pair vs
        //      R5's 192 cvt). Per-accumulator FMA order bit-identical to all
        //      prior verified rounds: aA[ch][0] receives T[2j],T[2j+1] against
        //      Y[2j],Y[2j+1] in j order, etc. cu/cv LAUNDERED per j so LICM
        //      cannot hoist the 64 products out of the P loop (= the R2 spill).
        double aA[3][4], aB[3][4];
        #pragma unroll
        for (int ch = 0; ch < 3; ++ch)
            #pragma unroll
            for (int k = 0; k < 4; ++k) { aA[ch][k] = 0.0; aB[ch][k] = 0.0; }

        #pragma unroll
        for (int j = 0; j < 8; ++j) {
            __builtin_amdgcn_sched_barrier(0);
            #pragma unroll
            for (int k = 0; k < 8; ++k) {
                asm volatile("" : "+v"(cu[k]));   // fresh defs: no LICM/CSE
                asm volatile("" : "+v"(cv[k]));
            }
            const int x0 = (2 * j) >> 3;          // 0 or 1
            const int y0 = (2 * j) & 7;           // 0,2,4,6
            // T[2j],T[2j+1],T[2j+16],...,T[2j+49] — same values as the table
            const double t0 = (double)(cu[x0]     * cv[y0]);
            const double t1 = (double)(cu[x0]     * cv[y0 + 1]);
            const double t2 = (double)(cu[x0 + 2] * cv[y0]);
            const double t3 = (double)(cu[x0 + 2] * cv[y0 + 1]);
            const double t4 = (double)(cu[x0 + 4] * cv[y0]);
            const double t5 = (double)(cu[x0 + 4] * cv[y0 + 1]);
            const double t6 = (double)(cu[x0 + 6] * cv[y0]);
            const double t7 = (double)(cu[x0 + 6] * cv[y0 + 1]);
            #pragma unroll
            for (int ch = 0; ch < 3; ++ch) {
                __builtin_amdgcn_sched_barrier(0);   // bound live loads (8 double2)
                const double2* __restrict__ YA = (const double2*)&sYd[0][ch][0];
                const double2* __restrict__ YB = (const double2*)&sYd[1][ch][0];
                const double2 u0 = YA[j];
                const double2 u1 = YA[j + 8];
                const double2 u2 = YA[j + 16];
                const double2 u3 = YA[j + 24];
                const double2 w0 = YB[j];
                const double2 w1 = YB[j + 8];
                const double2 w2 = YB[j + 16];
                const double2 w3 = YB[j + 24];
                aA[ch][0] = __builtin_fma(t0, u0.x, aA[ch][0]);
                aA[ch][0] = __builtin_fma(t1, u0.y, aA[ch][0]);
                aA[ch][1] = __builtin_fma(t2, u1.x, aA[ch][1]);
                aA[ch][1] = __builtin_fma(t3, u1.y, aA[ch][1]);
                aA[ch][2] = __builtin_fma(t4, u2.x, aA[ch][2]);
                aA[ch][2] = __builtin_fma(t5, u2.y, aA[ch][2]);
                aA[ch][3] = __builtin_fma(t6, u3.x, aA[ch][3]);
                aA[ch][3] = __builtin_fma(t7, u3.y, aA[ch][3]);
                aB[ch][0] = __builtin_fma(t0, w0.x, aB[ch][0]);
                aB[ch][0] = __builtin_fma(t1, w0.y, aB[ch][0]);
                aB[ch][1] = __builtin_fma(t2, w1.x, aB[ch][1]);
                aB[ch][1] = __builtin_fma(t3, w1.y, aB[ch][1]);
                aB[ch][2] = __builtin_fma(t4, w2.x, aB[ch][2]);
                aB[ch][2] = __builtin_fma(t5, w2.y, aB[ch][2]);
                aB[ch][3] = __builtin_fma(t6, w3.x, aB[ch][3]);
                aB[ch][3] = __builtin_fma(t7, w3.y, aB[ch][3]);
            }
        }
        __builtin_amdgcn_sched_barrier(0);

        // ---- diff-round quant (per-value op sequence identical to prior rounds) ----
        float Fv[2][3];
        #pragma unroll
        for (int ch = 0; ch < 3; ++ch) {
            const double SA = (aA[ch][0] + aA[ch][1]) + (aA[ch][2] + aA[ch][3]);
            const double SB = (aB[ch][0] + aB[ch][1]) + (aB[ch][2] + aB[ch][3]);
            const double qtd = (ch == 0) ? (double)yqf : (double)cqf;
            const double dq  = qtd * aaD;
            {
                const double f = (mQ * SA) / qtd;   // true f64 divide
                const double rr = __builtin_rint(f);
                const double d = f - rr;
                Fv[0][ch] = (float)((rr + (d * d) * d) * dq);
            }
            {
                const double f = (mQ * SB) / qtd;
                const double rr = __builtin_rint(f);
                const double d = f - rr;
                Fv[1][ch] = (float)((rr + (d * d) * d) * dq);
            }
        }
        #pragma unroll
        for (int blk = 0; blk < 2; ++blk)
            #pragma unroll
            for (int ch = 0; ch < 3; ++ch)
                sF[blk][ch][lane] = Fv[blk][ch];
        __syncthreads();

        // ---- stage 1: G[u][y] = sum_v c[y][v]*F[u][v]; store transposed [y][u] ----
        {
            const float4 cy0 = *(const float4*)&sC[py * 8];
            const float4 cy1 = *(const float4*)&sC[py * 8 + 4];
            #pragma unroll
            for (int blk = 0; blk < 2; ++blk)
                #pragma unroll
                for (int ch = 0; ch < 3; ++ch) {
                    const float4 f0 = *(const float4*)&sF[blk][ch][px * 8];
                    const float4 f1 = *(const float4*)&sF[blk][ch][px * 8 + 4];
                    float g = 0.0f;
                    g += cy0.x * f0.x; g += cy0.y * f0.y;
                    g += cy0.z * f0.z; g += cy0.w * f0.w;
                    g += cy1.x * f1.x; g += cy1.y * f1.y;
                    g += cy1.z * f1.z; g += cy1.w * f1.w;
                    sGt[blk][ch][py * 12 + px] = g;   // (yy=py, uu=px)
                }
        }
        __syncthreads();

        // ---- stage 2 + color-back: two ADJACENT pixels (px, col0/col0+1) of blkL ----
        float r0[3], r1[3];
        {
            const float4 cx0 = *(const float4*)&sC[px * 8];
            const float4 cx1 = *(const float4*)&sC[px * 8 + 4];
            #pragma unroll
            for (int ch = 0; ch < 3; ++ch) {
                const float4 ga0 = *(const float4*)&sGt[blkL][ch][col0 * 12];
                const float4 ga1 = *(const float4*)&sGt[blkL][ch][col0 * 12 + 4];
                const float4 gb0 = *(const float4*)&sGt[blkL][ch][(col0 + 1) * 12];
                const float4 gb1 = *(const float4*)&sGt[blkL][ch][(col0 + 1) * 12 + 4];
                float p0 = 0.0f, p1 = 0.0f;
                p0 += cx0.x * ga0.x; p0 += cx0.y * ga0.y;
                p0 += cx0.z * ga0.z; p0 += cx0.w * ga0.w;
                p0 += cx1.x * ga1.x; p0 += cx1.y * ga1.y;
                p0 += cx1.z * ga1.z; p0 += cx1.w * ga1.w;
                p1 += cx0.x * gb0.x; p1 += cx0.y * gb0.y;
                p1 += cx0.z * gb0.z; p1 += cx0.w * gb0.w;
                p1 += cx1.x * gb1.x; p1 += cx1.y * gb1.y;
                p1 += cx1.z * gb1.z; p1 += cx1.w * gb1.w;
                r0[ch] = p0 * 0.25f;
                r1[ch] = p1 * 0.25f;
            }
        }
        {
            const float yvA = r0[0] + 128.0f, cbA = r0[1], crA = r0[2];
            const float yvB = r1[0] + 128.0f, cbB = r1[1], crB = r1[2];
            const float roA = yvA + 1.402f * crA;
            const float goA = yvA - 0.344136f * cbA - 0.714136f * crA;
            const float boA = yvA + 1.772f * cbA;
            const float roB = yvB + 1.402f * crB;
            const float goB = yvB - 0.344136f * cbB - 0.714136f * crB;
            const float boB = yvB + 1.772f * cbB;
            const size_t ob = rowbase + 2 * py;   // global cols: blkL*8+col0 == 2*py
            *(float2*)(out + ob) =
                make_float2(clamp255(roA), clamp255(roB));
            *(float2*)(out + ob + PLANE) =
                make_float2(clamp255(goA), clamp255(goB));
            *(float2*)(out + ob + 2 * (size_t)PLANE) =
                make_float2(clamp255(boA), clamp255(boB));
        }
    }
}

extern "C" void kernel_launch(void* const* d_in, const int* in_sizes, int n_in,
                              void* d_out, int out_size, void* d_ws, size_t ws_size,
                              hipStream_t stream) {
    const float* in = (const float*)d_in[0];
    float* out = (float*)d_out;
    jpeg_kernel<<<NWG, 64, 0, stream>>>(in, out);
}

// Round 7
// 129.456 us; speedup vs baseline: 2.9405x; 1.1665x over previous
//
#include <hip/hip_runtime.h>

namespace {

constexpr int BATCH = 16;
constexpr int HH = 512;
constexpr int WW = 512;
constexpr int PLANE = HH * WW;
constexpr int NPAIR = BATCH * (HH / 8) * (WW / 16);  // 32768 block-pairs
constexpr int NWG = 8192;                            // ITERS=4

// ---- numpy-faithful cosine table (decision-path numerics) ----
constexpr double PI64 = 3.141592653589793;
constexpr double PI_LO = 1.2246467991473532e-16;
constexpr double PI_HI = (double)((long long)(PI64 * 17592186044416.0)) / 17592186044416.0;
constexpr double PI_MID = PI64 - PI_HI;

constexpr double CD9[9] = {
    1.0,
    0.9807852804032304491,
    0.9238795325112867561,
    0.8314696123025452371,
    0.7071067811865475244,
    0.5555702330196022248,
    0.3826834323650897717,
    0.1950903220161282678,
    0.0};
constexpr double cos_tab(int m) {
    m %= 32;
    double s = 1.0;
    if (m > 16) m = 32 - m;
    if (m > 8) { s = -1.0; m = 16 - m; }
    return s * CD9[m];
}
constexpr double sin_tab(int m) { return cos_tab(m + 24); }

constexpr double cx64(int K) {
    float Kf = (float)K;
    float p32 = (float)PI64;
    float t32 = Kf * p32;
    double F = (double)t32;
    double E = ((F - (double)K * PI_HI) - (double)K * PI_MID) - (double)K * PI_LO;
    double r = E / 16.0;
    double C = cos_tab(K), S = sin_tab(K);
    double cr = 1.0 - 0.5 * r * r;
    double sr = r - (r * r * r) / 6.0;
    return C * cr - S * sr;
}
constexpr float cx32(int x, int u) { return (float)cx64((2 * x + 1) * u); }

struct C32A { float c[64]; };
constexpr C32A make_c32f() {
    C32A a{};
    for (int x = 0; x < 8; ++x)
        for (int u = 0; u < 8; ++u)
            a.c[x * 8 + u] = cx32(x, u);
    return a;
}
constexpr C32A C32F = make_c32f();

constexpr float YQ[64] = {
    16, 11, 10, 16, 24, 40, 51, 61,
    12, 12, 14, 19, 26, 58, 60, 55,
    14, 13, 16, 24, 40, 57, 69, 56,
    14, 17, 22, 29, 51, 87, 80, 62,
    18, 22, 37, 56, 68, 109, 103, 77,
    24, 35, 55, 64, 81, 104, 113, 92,
    49, 64, 78, 87, 103, 121, 120, 101,
    72, 92, 95, 98, 112, 100, 103, 99};

constexpr float CQ[64] = {
    17, 18, 24, 47, 99, 99, 99, 99,
    18, 21, 26, 66, 99, 99, 99, 99,
    24, 26, 56, 99, 99, 99, 99, 99,
    47, 66, 99, 99, 99, 99, 99, 99,
    99, 99, 99, 99, 99, 99, 99, 99,
    99, 99, 99, 99, 99, 99, 99, 99,
    99, 99, 99, 99, 99, 99, 99, 99,
    99, 99, 99, 99, 99, 99, 99, 99};

constexpr float AL32 = (float)0.7071067811865475244;

} // namespace

// fp64 color transform — bit-identical (decision path).
__device__ __forceinline__ void color_f64(float Rf, float Gf, float Bf,
                                          double& yv, double& cbv, double& crv) {
    const double rv = ((double)Rf + 1.0) * 127.5;
    const double gv = ((double)Gf + 1.0) * 127.5;
    const double bv = ((double)Bf + 1.0) * 127.5;
    yv = ((double)0.299f * rv + (double)0.587f * gv) + (double)0.114f * bv;
    yv = yv - 128.0;
    cbv = ((double)-0.168736f * rv + (double)-0.331264f * gv) + (double)0.5f * bv;
    cbv = (cbv + 128.0) - 128.0;
    crv = ((double)0.5f * rv + (double)-0.418688f * gv) + (double)-0.081312f * bv;
    crv = (crv + 128.0) - 128.0;
}

__device__ __forceinline__ float clamp255(float x) {
    return fminf(fmaxf(x, 0.0f), 255.0f) * (1.0f / 255.0f);
}

// One wave = one PAIR of horizontally adjacent 8x8 blocks per iteration.
// SEPARABLE f64 DCT: S[u][v] = sum_y cvD[v][y] * ( sum_x cuD[u][x] * Y[x][y] ).
// T is rank-1 (T[x,y,u,v] = c[x][u]*c[y][v]), so this equals the full 64-dot
// up to f64 summation order (~1e-16 relative); rint decisions are unaffected
// except on a measure-zero boundary set (verified: absmax must stay constant).
__global__ __launch_bounds__(64, 4) void jpeg_kernel(const float* __restrict__ in,
                                                     float* __restrict__ out) {
    __shared__ __align__(16) double sYd[2][3][64];   // 3072 B: pair x ch x [x*8+y]
    __shared__ __align__(16) char   sScr[5376];      // sV/sGt (aliased) + sF
    __shared__ __align__(16) float  sC[64];          // fp32 cosines for IDCT

    // region map (lifetimes disjoint, barrier-ordered):
    //   [0,3840):   double sV[2][3][80]  — DCT stage-A output, rows padded to 10
    //   [0,2304):   float  sGt[2][3][96] — idct stage-1 (aliases sV; used later)
    //   [3840,5376): float sF[2][3][64]  — quantized coefficients
    double (*sV)[3][80]  = reinterpret_cast<double(*)[3][80]>(sScr);
    float  (*sGt)[3][96] = reinterpret_cast<float(*)[3][96]>(sScr);
    float  (*sF)[3][64]  = reinterpret_cast<float(*)[3][64]>(sScr + 3840);

    const int lane = threadIdx.x;     // 0..63
    const int px = lane >> 3;         // row within block / u-index
    const int py = lane & 7;          // col index        / v-index

    sC[lane] = C32F.c[lane];

    // per-lane f64 DCT factors (32 VGPRs, deliberately persistent):
    //   cuD[x] = (double)c[x][u=px],  cvD[y] = (double)c[y][v=py]
    double cuD[8], cvD[8];
    #pragma unroll
    for (int k = 0; k < 8; ++k) {
        cuD[k] = (double)C32F.c[k * 8 + px];
        cvD[k] = (double)C32F.c[k * 8 + py];
    }

    // quant constants; f64 values re-derived per use exactly as the old QD table.
    const float yqf  = YQ[lane];
    const float cqf  = CQ[lane];
    const float aa32 = (px == 0 ? AL32 : 1.0f) * (py == 0 ? AL32 : 1.0f);
    const double aaD = (double)aa32;
    const double mQ  = (double)(aa32 * 0.25f);

    const int blkL = py >> 2;         // which block this lane's pixel-pair is in
    const int col0 = (py & 3) * 2;    // first of two adjacent columns in that block

    #pragma unroll 1
    for (int P = blockIdx.x; P < NPAIR; P += NWG) {
        const int b = P >> 11;              // image (2048 pairs per image)
        const int p2 = P & 2047;
        const int by = p2 >> 5;             // block row (64 rows)
        const int pbx = p2 & 31;            // pair col (32 pairs per row)
        const size_t rowbase = (size_t)b * 3 * PLANE + (size_t)(by * 8 + px) * WW
                             + (size_t)(pbx * 16);

        // ---- full-cache-line loads: float2 per lane per channel ----
        const float2 Rp = *(const float2*)(in + rowbase + 2 * py);
        const float2 Gp = *(const float2*)(in + rowbase + PLANE + 2 * py);
        const float2 Bp = *(const float2*)(in + rowbase + 2 * (size_t)PLANE + 2 * py);

        __syncthreads();   // B1: prior iter's sYd stage-A reads + sGt reads done

        {
            double y0, cb0, cr0, y1, cb1, cr1;
            color_f64(Rp.x, Gp.x, Bp.x, y0, cb0, cr0);
            color_f64(Rp.y, Gp.y, Bp.y, y1, cb1, cr1);
            const int si = px * 8 + col0;
            *(double2*)&sYd[blkL][0][si] = make_double2(y0, y1);
            *(double2*)&sYd[blkL][1][si] = make_double2(cb0, cb1);
            *(double2*)&sYd[blkL][2][si] = make_double2(cr0, cr1);
        }
        __syncthreads();   // B2: sYd complete

        // ---- DCT stage A: V[u=px][y=py] = sum_x cuD[x] * Y[x][py]  (6 dots) ----
        #pragma unroll
        for (int blk = 0; blk < 2; ++blk)
            #pragma unroll
            for (int ch = 0; ch < 3; ++ch) {
                const double* __restrict__ Y = &sYd[blk][ch][0];
                double v = 0.0;
                #pragma unroll
                for (int x = 0; x < 8; ++x)
                    v = __builtin_fma(cuD[x], Y[x * 8 + py], v);
                sV[blk][ch][px * 10 + py] = v;
            }
        __syncthreads();   // B3: sV complete

        // ---- DCT stage B + diff-round quant ----
        float Fv[2][3];
        #pragma unroll
        for (int ch = 0; ch < 3; ++ch) {
            const double* __restrict__ VA = &sV[0][ch][px * 10];
            const double* __restrict__ VB = &sV[1][ch][px * 10];
            double sA = 0.0, sB = 0.0;
            #pragma unroll
            for (int y = 0; y < 8; ++y) {
                sA = __builtin_fma(cvD[y], VA[y], sA);
                sB = __builtin_fma(cvD[y], VB[y], sB);
            }
            const double qtd = (ch == 0) ? (double)yqf : (double)cqf;
            const double dq  = qtd * aaD;
            {
                const double f = (mQ * sA) / qtd;   // true f64 divide
                const double rr = __builtin_rint(f);
                const double d = f - rr;
                Fv[0][ch] = (float)((rr + (d * d) * d) * dq);
            }
            {
                const double f = (mQ * sB) / qtd;
                const double rr = __builtin_rint(f);
                const double d = f - rr;
                Fv[1][ch] = (float)((rr + (d * d) * d) * dq);
            }
        }
        #pragma unroll
        for (int blk = 0; blk < 2; ++blk)
            #pragma unroll
            for (int ch = 0; ch < 3; ++ch)
                sF[blk][ch][lane] = Fv[blk][ch];
        __syncthreads();   // B4: sV reads done (sGt may now overwrite), sF visible

        // ---- idct stage 1: G[u][y] = sum_v c[y][v]*F[u][v]; store transposed [y][u] ----
        {
            const float4 cy0 = *(const float4*)&sC[py * 8];
            const float4 cy1 = *(const float4*)&sC[py * 8 + 4];
            #pragma unroll
            for (int blk = 0; blk < 2; ++blk)
                #pragma unroll
                for (int ch = 0; ch < 3; ++ch) {
                    const float4 f0 = *(const float4*)&sF[blk][ch][px * 8];
                    const float4 f1 = *(const float4*)&sF[blk][ch][px * 8 + 4];
                    float g = 0.0f;
                    g += cy0.x * f0.x; g += cy0.y * f0.y;
                    g += cy0.z * f0.z; g += cy0.w * f0.w;
                    g += cy1.x * f1.x; g += cy1.y * f1.y;
                    g += cy1.z * f1.z; g += cy1.w * f1.w;
                    sGt[blk][ch][py * 12 + px] = g;   // (yy=py, uu=px)
                }
        }
        __syncthreads();   // B5: sGt complete

        // ---- idct stage 2 + color-back: two ADJACENT pixels of blkL ----
        float r0[3], r1[3];
        {
            const float4 cx0 = *(const float4*)&sC[px * 8];
            const float4 cx1 = *(const float4*)&sC[px * 8 + 4];
            #pragma unroll
            for (int ch = 0; ch < 3; ++ch) {
                const float4 ga0 = *(const float4*)&sGt[blkL][ch][col0 * 12];
                const float4 ga1 = *(const float4*)&sGt[blkL][ch][col0 * 12 + 4];
                const float4 gb0 = *(const float4*)&sGt[blkL][ch][(col0 + 1) * 12];
                const float4 gb1 = *(const float4*)&sGt[blkL][ch][(col0 + 1) * 12 + 4];
                float p0 = 0.0f, p1 = 0.0f;
                p0 += cx0.x * ga0.x; p0 += cx0.y * ga0.y;
                p0 += cx0.z * ga0.z; p0 += cx0.w * ga0.w;
                p0 += cx1.x * ga1.x; p0 += cx1.y * ga1.y;
                p0 += cx1.z * ga1.z; p0 += cx1.w * ga1.w;
                p1 += cx0.x * gb0.x; p1 += cx0.y * gb0.y;
                p1 += cx0.z * gb0.z; p1 += cx0.w * gb0.w;
                p1 += cx1.x * gb1.x; p1 += cx1.y * gb1.y;
                p1 += cx1.z * gb1.z; p1 += cx1.w * gb1.w;
                r0[ch] = p0 * 0.25f;
                r1[ch] = p1 * 0.25f;
            }
        }
        {
            const float yvA = r0[0] + 128.0f, cbA = r0[1], crA = r0[2];
            const float yvB = r1[0] + 128.0f, cbB = r1[1], crB = r1[2];
            const float roA = yvA + 1.402f * crA;
            const float goA = yvA - 0.344136f * cbA - 0.714136f * crA;
            const float boA = yvA + 1.772f * cbA;
            const float roB = yvB + 1.402f * crB;
            const float goB = yvB - 0.344136f * cbB - 0.714136f * crB;
            const float boB = yvB + 1.772f * cbB;
            const size_t ob = rowbase + 2 * py;   // global cols: blkL*8+col0 == 2*py
            *(float2*)(out + ob) =
                make_float2(clamp255(roA), clamp255(roB));
            *(float2*)(out + ob + PLANE) =
                make_float2(clamp255(goA), clamp255(goB));
            *(float2*)(out + ob + 2 * (size_t)PLANE) =
                make_float2(clamp255(boA), clamp255(boB));
        }
    }
}

extern "C" void kernel_launch(void* const* d_in, const int* in_sizes, int n_in,
                              void* d_out, int out_size, void* d_ws, size_t ws_size,
                              hipStream_t stream) {
    const float* in = (const float*)d_in[0];
    float* out = (float*)d_out;
    jpeg_kernel<<<NWG, 64, 0, stream>>>(in, out);
}